// Round 4
// baseline (375.315 us; speedup 1.0000x reference)
//
#include <hip/hip_runtime.h>
#include <math.h>

#define DIM 512
#define KCB 1024
#define BM  128
#define THREADS 512
// ws layout (bytes)
#define CBT_OFF   0u         // CB fp16 swizzled [2 halves][8 chunks][4096 slots*16B] = 1 MB
#define CNORM_OFF 1048576u   // 4 KB
#define HIST_OFF  1052672u   // 4 KB
#define LOSS_OFF  1056768u   // 64 B
// X fp16 image lives inside each block's own 256-KB output span:
//   block b: bytes [16 + b*262144, 16 + b*262144 + 131072), A-fragment-major order.

typedef _Float16 half8 __attribute__((ext_vector_type(8)));
typedef float floatx4 __attribute__((ext_vector_type(4)));

__device__ __forceinline__ void g2l16(const void* g, void* l) {
    __builtin_amdgcn_global_load_lds(
        (const __attribute__((address_space(1))) unsigned int*)g,
        (__attribute__((address_space(3))) unsigned int*)l, 16, 0, 0);
}

__device__ __forceinline__ half8 cvt8(float4 v0, float4 v1) {
    half8 h;
    h[0] = (_Float16)v0.x; h[1] = (_Float16)v0.y; h[2] = (_Float16)v0.z; h[3] = (_Float16)v0.w;
    h[4] = (_Float16)v1.x; h[5] = (_Float16)v1.y; h[6] = (_Float16)v1.z; h[7] = (_Float16)v1.w;
    return h;
}

// ---------------- prep: X -> A-frag-major fp16 image (+ Sum x^2), CB -> swizzled fp16 (+ cnorm) ----------------
__global__ __launch_bounds__(256) void prep(const float* __restrict__ X,
                                            const float* __restrict__ CB,
                                            char* __restrict__ ob,
                                            char* __restrict__ ws,
                                            float* __restrict__ loss_acc) {
    const int t = threadIdx.x;
    const int b = blockIdx.x;
    if (b < 1024) {
        // one 64-row group per block; 4096 slots of 16 B, written contiguously
        const int R = b;
        char* base = ob + 16 + (size_t)(R >> 1) * 262144 + (size_t)(R & 1) * 65536;
        float ss = 0.f;
#pragma unroll
        for (int it = 0; it < 16; ++it) {
            int s = it * 256 + t;
            int dc = s >> 9;          // chunk 0..7
            int f  = (s >> 6) & 7;    // frag slab = ks*4+ar
            int l  = s & 63;          // lane slot: row=ar*16+(l&15), d-quad=(l>>4)
            int row = R * 64 + (f & 3) * 16 + (l & 15);
            int dbase = dc * 64 + (f >> 2) * 32 + (l >> 4) * 8;
            const float4* p = (const float4*)(X + (size_t)row * DIM + dbase);
            float4 v0 = p[0], v1 = p[1];
            *(half8*)(base + (size_t)s * 16) = cvt8(v0, v1);
            ss += v0.x * v0.x + v0.y * v0.y + v0.z * v0.z + v0.w * v0.w
                + v1.x * v1.x + v1.y * v1.y + v1.z * v1.z + v1.w * v1.w;
        }
#pragma unroll
        for (int off = 32; off > 0; off >>= 1) ss += __shfl_xor(ss, off);
        if ((t & 63) == 0) atomicAdd(loss_acc, ss);   // Sum x^2 contribution
    } else {
        // CB: one code per wave (256 blocks x 4 waves = 1024 codes)
        const int w = t >> 6, lane = t & 63;
        const int dc = lane >> 3, g = lane & 7;
        int k = (b - 1024) * 4 + w;
        const float4* src = (const float4*)(CB + (size_t)k * DIM);
        float4 v0 = src[lane * 2];
        float4 v1 = src[lane * 2 + 1];
        int h = k >> 9, kl = k & 511;
        int slot = kl * 8 + (g ^ (kl & 7));
        *(half8*)(ws + CBT_OFF + (size_t)h * 524288 + (size_t)dc * 65536 + (size_t)slot * 16) = cvt8(v0, v1);
        float s = v0.x * v0.x + v0.y * v0.y + v0.z * v0.z + v0.w * v0.w
                + v1.x * v1.x + v1.y * v1.y + v1.z * v1.z + v1.w * v1.w;
#pragma unroll
        for (int off = 32; off > 0; off >>= 1) s += __shfl_xor(s, off);
        if (lane == 0) ((float*)(ws + CNORM_OFF))[k] = s;
    }
}

// ---------------- main: dbuf-prefetched CB DMA + global A-frags + MFMA + fused argmin ----------------
__global__ __launch_bounds__(THREADS, 2) void vq_main(
    char* __restrict__ ob, const float* __restrict__ CB32,
    const char* __restrict__ ws, int* __restrict__ hist,
    float* __restrict__ loss_acc) {
    extern __shared__ char smem[];               // CBs[0] @0, CBs[1] @65536 (131072 B)
    float* argS = (float*)smem;                  // [4][128] overlay (epilogue)
    int*   argI = (int*)(smem + 2048);           // [4][128]
    int*   idxF = (int*)(smem + 4096);           // [128]

    const int t = threadIdx.x;
    const int lane = t & 63;
    const int w = __builtin_amdgcn_readfirstlane(t >> 6);
    const int rg = w >> 2, cg = w & 3;           // 2 row-groups x 4 col-groups
    const int q = lane >> 4, ln = lane & 15, pg = ln & 7;
    const int rowbase = blockIdx.x * BM;
    const float* cnorm = (const float*)(ws + CNORM_OFF);
    const char* xb = ob + 16 + (size_t)blockIdx.x * 262144 + (size_t)rg * 65536;

    float bestS[16];
    int bestI[16];
#pragma unroll
    for (int li = 0; li < 16; ++li) { bestS[li] = 3.0e38f; bestI[li] = 0; }

    floatx4 acc[4][8];

    // prime: DMA (h=0,dc=0) -> buf0
#pragma unroll
    for (int i = 0; i < 8; ++i) {
        int sb = (i * 8 + w) * 64;
        g2l16(ws + CBT_OFF + (size_t)(sb + lane) * 16, smem + (size_t)sb * 16);
    }

#pragma unroll
    for (int it = 0; it < 16; ++it) {
        const int h = it >> 3, dc = it & 7;
        char* buf = smem + (size_t)(it & 1) * 65536;
        __syncthreads();   // drains buf's DMA (issued last iter, covered by compute)
        // A-frags first (older in vmcnt FIFO: their waits leave the prefetch in flight)
        half8 av[8];
        const char* xc = xb + dc * 8192;
#pragma unroll
        for (int f = 0; f < 8; ++f)
            av[f] = *(const half8*)(xc + f * 1024 + lane * 16);
        __builtin_amdgcn_sched_barrier(0);
        if (it < 15) {     // prefetch next chunk into the other buffer
            const int it2 = it + 1;
            const char* src = ws + CBT_OFF + (size_t)(it2 >> 3) * 524288 + (size_t)(it2 & 7) * 65536;
            char* nbuf = smem + (size_t)(it2 & 1) * 65536;
#pragma unroll
            for (int i = 0; i < 8; ++i) {
                int sb = (i * 8 + w) * 64;
                g2l16(src + (size_t)(sb + lane) * 16, nbuf + (size_t)sb * 16);
            }
        }
        if ((it & 7) == 0) {
#pragma unroll
            for (int ar = 0; ar < 4; ++ar)
#pragma unroll
                for (int bc = 0; bc < 8; ++bc) acc[ar][bc] = (floatx4){0.f, 0.f, 0.f, 0.f};
        }
#pragma unroll
        for (int ks = 0; ks < 2; ++ks) {
            const int sw = ((ks << 2) | q) ^ pg;
#pragma unroll
            for (int bc = 0; bc < 8; ++bc) {
                half8 bfr = *(const half8*)(buf + (size_t)(cg * 128 + bc * 16 + ln) * 128 + sw * 16);
#pragma unroll
                for (int ar = 0; ar < 4; ++ar)
                    acc[ar][bc] = __builtin_amdgcn_mfma_f32_16x16x32_f16(av[ks * 4 + ar], bfr, acc[ar][bc], 0, 0, 0);
            }
        }
        if ((it & 7) == 7) {   // fold this half (ascending col; strict < = first occurrence)
#pragma unroll
            for (int bc = 0; bc < 8; ++bc) {
                int col = h * 512 + cg * 128 + bc * 16 + ln;
                float cn = cnorm[col];
#pragma unroll
                for (int ar = 0; ar < 4; ++ar)
#pragma unroll
                    for (int r = 0; r < 4; ++r) {
                        float s = fmaf(-2.f, acc[ar][bc][r], cn);
                        int li = ar * 4 + r;
                        if (s < bestS[li]) { bestS[li] = s; bestI[li] = col; }
                    }
            }
        }
    }

    // butterfly across the 16 ln-lanes (lowest index wins ties)
#pragma unroll
    for (int off = 1; off <= 8; off <<= 1)
#pragma unroll
        for (int li = 0; li < 16; ++li) {
            float s2 = __shfl_xor(bestS[li], off);
            int i2 = __shfl_xor(bestI[li], off);
            if (s2 < bestS[li] || (s2 == bestS[li] && i2 < bestI[li])) {
                bestS[li] = s2; bestI[li] = i2;
            }
        }
    // overlay sits in CBs[0]; any lagging wave is in it=15 reading CBs[1] -> safe
    if (ln == 0) {
#pragma unroll
        for (int li = 0; li < 16; ++li) {
            int row = rg * 64 + (li >> 2) * 16 + q * 4 + (li & 3);
            argS[cg * 128 + row] = bestS[li];
            argI[cg * 128 + row] = bestI[li];
        }
    }
    __syncthreads();
    if (t < BM) {
        float s = argS[t];
        int bi = argI[t];
#pragma unroll
        for (int c = 1; c < 4; ++c) {   // ascending col-group order
            float s2 = argS[c * 128 + t];
            int i2 = argI[c * 128 + t];
            if (s2 < s || (s2 == s && i2 < bi)) { s = s2; bi = i2; }
        }
        idxF[t] = bi;
        atomicAdd(&hist[bi], 1);
        float l = s;   // s* = ||c||^2 - 2 x.c ; Sum x^2 added by prep
#pragma unroll
        for (int off = 32; off > 0; off >>= 1) l += __shfl_xor(l, off);
        if ((t & 63) == 0) atomicAdd(loss_acc, l);
    }
    __syncthreads();
    // gather + coalesced write (overwrites this block's own X-image span only)
    float* outq = (float*)ob + 1;
    for (int m = 0; m < BM; ++m) {
        int bi = idxF[m];
        outq[(size_t)(rowbase + m) * DIM + t] = CB32[(size_t)bi * DIM + t];
    }
}

// ---------------- finalize: loss scalar + perplexity ----------------
__global__ __launch_bounds__(256) void finalize_kernel(
    const int* __restrict__ hist, const float* __restrict__ loss_acc,
    float* __restrict__ out, int n_rows, int q_count) {
    __shared__ float wsum[4];
    int t = threadIdx.x;
    float invN = 1.f / (float)n_rows;
    float hsum = 0.f;
    for (int k = t; k < KCB; k += 256) {
        float p = (float)hist[k] * invN;
        hsum += p * logf(p + 1e-10f);
    }
#pragma unroll
    for (int off = 32; off > 0; off >>= 1) hsum += __shfl_xor(hsum, off);
    if ((t & 63) == 0) wsum[t >> 6] = hsum;
    __syncthreads();
    if (t == 0) {
        float H = -(wsum[0] + wsum[1] + wsum[2] + wsum[3]);
        out[0] = loss_acc[0] * (1.25f / (float)q_count);  // (Sum s* + Sum x^2) * 1.25 / (N*D)
        out[1 + q_count] = expf(H);
    }
}

extern "C" void kernel_launch(void* const* d_in, const int* in_sizes, int n_in,
                              void* d_out, int out_size, void* d_ws, size_t ws_size,
                              hipStream_t stream) {
    const float* X = (const float*)d_in[0];
    const float* CB = (const float*)d_in[1];
    char* ob = (char*)d_out;
    char* ws = (char*)d_ws;
    int N = in_sizes[0] / DIM;  // 65536 rows

    hipMemsetAsync(ws + HIST_OFF, 0, 4096 + 64, stream);
    prep<<<1024 + 256, 256, 0, stream>>>(X, CB, ob, ws, (float*)(ws + LOSS_OFF));

    vq_main<<<N / BM, THREADS, 131072, stream>>>(ob, CB, ws,
                                                 (int*)(ws + HIST_OFF),
                                                 (float*)(ws + LOSS_OFF));
    finalize_kernel<<<1, 256, 0, stream>>>((int*)(ws + HIST_OFF),
                                           (float*)(ws + LOSS_OFF),
                                           (float*)d_out, N, N * DIM);
}